// Round 1
// baseline (64.758 us; speedup 1.0000x reference)
//
#include <hip/hip_runtime.h>
#include <hip/hip_bf16.h>
#include <stdint.h>

// Problem: out[N,OUT] = x[N,IN] @ weight[OUT,IN]^T + bias[OUT]
// N=4096, IN(K)=2048, OUT=2048, all fp32 in/out.
#define NROWS 4096
#define KDIM  2048
#define ODIM  2048

typedef __bf16 bf16x8 __attribute__((ext_vector_type(8)));
typedef float  f32x4  __attribute__((ext_vector_type(4)));
typedef unsigned short u16;
typedef unsigned int   u32;

__device__ __forceinline__ u16 f32_to_bf16_rne(float f) {
  u32 u = __builtin_bit_cast(u32, f);
  u += 0x7FFFu + ((u >> 16) & 1u);   // round-to-nearest-even (inputs are finite normals)
  return (u16)(u >> 16);
}

// fp32 -> bf16 conversion, vectorized: float4 in (16B), ushort4 out (8B)
__global__ void cvt_f32_to_bf16(const float* __restrict__ in,
                                u16* __restrict__ out, int n4) {
  int i = blockIdx.x * blockDim.x + threadIdx.x;
  int stride = gridDim.x * blockDim.x;
  for (; i < n4; i += stride) {
    float4 v = reinterpret_cast<const float4*>(in)[i];
    ushort4 o;
    o.x = f32_to_bf16_rne(v.x);
    o.y = f32_to_bf16_rne(v.y);
    o.z = f32_to_bf16_rne(v.z);
    o.w = f32_to_bf16_rne(v.w);
    reinterpret_cast<ushort4*>(out)[i] = o;
  }
}

// async global->LDS, 16B per lane; LDS dest must be wave-uniform base (+lane*16 in HW)
__device__ __forceinline__ void async16(const u16* g, const u16* l) {
  __builtin_amdgcn_global_load_lds((const __attribute__((address_space(1))) u32*)g,
                                   (__attribute__((address_space(3))) u32*)l,
                                   16, 0, 0);
}

// m97-structure bf16 GEMM-BT: C[M,N] = A[M,K] * B[N,K]^T + bias
// 128x128 tile, BK=32, 256 threads = 4 waves (2x2), each wave 64x64 (4x4 frags of 16x16x32)
__global__ void __launch_bounds__(256)
gemm_bt_bf16(const u16* __restrict__ A, const u16* __restrict__ B,
             const float* __restrict__ bias, float* __restrict__ C) {
  __shared__ __align__(16) u16 As[128 * 32];
  __shared__ __align__(16) u16 Bs[128 * 32];

  const int t    = threadIdx.x;
  const int lane = t & 63;
  const int wave = t >> 6;
  const int wrow = wave >> 1;   // 0..1
  const int wcol = wave & 1;    // 0..1
  const int fr   = lane & 15;   // A-row / B-col / C-col within fragment
  const int fq   = lane >> 4;   // 0..3: k-chunk for A/B, row-group for C

  const int bx   = blockIdx.x;
  const int brow = (bx >> 4) * 128;  // 32 row-blocks
  const int bcol = (bx & 15) * 128;  // 16 col-blocks

  // ---- staging address setup (linear LDS layout [128][32] u16, 2 issues per tile) ----
  const int srow = t >> 2;          // 0..63 (row within half-tile)
  const int scol = (t & 3) * 8;     // k-offset, 8 bf16 = 16B per lane
  const u16* pA0 = A + (size_t)(brow + srow)      * KDIM + scol;
  const u16* pA1 = A + (size_t)(brow + 64 + srow) * KDIM + scol;
  const u16* pB0 = B + (size_t)(bcol + srow)      * KDIM + scol;
  const u16* pB1 = B + (size_t)(bcol + 64 + srow) * KDIM + scol;
  // wave-uniform LDS dests (lane*16B added by HW)
  u16* lA0 = As + wave * 512;
  u16* lA1 = As + 2048 + wave * 512;
  u16* lB0 = Bs + wave * 512;
  u16* lB1 = Bs + 2048 + wave * 512;

  f32x4 acc[4][4] = {};

  // fragment read offsets (elements): row*32 + k_chunk*8
  const int aoff = (wrow * 64 + fr) * 32 + fq * 8;  // + m*16*32
  const int boff = (wcol * 64 + fr) * 32 + fq * 8;  // + n*16*32

  for (int kt = 0; kt < KDIM / 32; ++kt) {
    __syncthreads();                 // prior iter's ds_reads done before overwrite
    async16(pA0, lA0);
    async16(pA1, lA1);
    async16(pB0, lB0);
    async16(pB1, lB1);
    pA0 += 32; pA1 += 32; pB0 += 32; pB1 += 32;
    __syncthreads();                 // compiler drains vmcnt before barrier

    bf16x8 af[4], bf[4];
#pragma unroll
    for (int m = 0; m < 4; ++m)
      af[m] = *reinterpret_cast<const bf16x8*>(As + aoff + m * 512);
#pragma unroll
    for (int n = 0; n < 4; ++n)
      bf[n] = *reinterpret_cast<const bf16x8*>(Bs + boff + n * 512);
#pragma unroll
    for (int m = 0; m < 4; ++m)
#pragma unroll
      for (int n = 0; n < 4; ++n)
        acc[m][n] = __builtin_amdgcn_mfma_f32_16x16x32_bf16(af[m], bf[n], acc[m][n], 0, 0, 0);
  }

  // ---- epilogue: C/D layout col=lane&15, row=(lane>>4)*4+reg ----
  float bv[4];
#pragma unroll
  for (int n = 0; n < 4; ++n)
    bv[n] = bias[bcol + wcol * 64 + n * 16 + fr];
#pragma unroll
  for (int m = 0; m < 4; ++m) {
    const int row0 = brow + wrow * 64 + m * 16 + fq * 4;
#pragma unroll
    for (int n = 0; n < 4; ++n) {
      const int col = bcol + wcol * 64 + n * 16 + fr;
      float* o = C + (size_t)row0 * ODIM + col;
#pragma unroll
      for (int j = 0; j < 4; ++j)
        o[(size_t)j * ODIM] = acc[m][n][j] + bv[n];
    }
  }
}

// correctness-only fallback if ws is too small (fp32, 16x16 LDS tiles)
__global__ void fallback_gemm(const float* __restrict__ x, const float* __restrict__ w,
                              const float* __restrict__ bias, float* __restrict__ out) {
  __shared__ float xs[16][17];
  __shared__ float wsm[16][17];
  const int tx = threadIdx.x & 15, ty = threadIdx.x >> 4;
  const int row = blockIdx.y * 16 + ty;
  const int colb = blockIdx.x * 16;
  float acc = 0.f;
  for (int k0 = 0; k0 < KDIM; k0 += 16) {
    xs[ty][tx]  = x[(size_t)row * KDIM + k0 + tx];
    wsm[ty][tx] = w[(size_t)(colb + ty) * KDIM + k0 + tx];
    __syncthreads();
#pragma unroll
    for (int kk = 0; kk < 16; ++kk)
      acc += xs[ty][kk] * wsm[tx][kk];
    __syncthreads();
  }
  out[(size_t)row * ODIM + colb + tx] = acc + bias[colb + tx];
}

extern "C" void kernel_launch(void* const* d_in, const int* in_sizes, int n_in,
                              void* d_out, int out_size, void* d_ws, size_t ws_size,
                              hipStream_t stream) {
  const float* x    = (const float*)d_in[0];
  const float* w    = (const float*)d_in[1];
  const float* bias = (const float*)d_in[2];
  float* out = (float*)d_out;

  const size_t needA = (size_t)NROWS * KDIM * sizeof(u16); // 16 MiB
  const size_t needB = (size_t)ODIM  * KDIM * sizeof(u16); //  8 MiB
  if (ws_size < needA + needB) {
    dim3 grid(ODIM / 16, NROWS / 16);
    fallback_gemm<<<grid, 256, 0, stream>>>(x, w, bias, out);
    return;
  }

  u16* xb = (u16*)d_ws;
  u16* wb = xb + (size_t)NROWS * KDIM;

  cvt_f32_to_bf16<<<2048, 256, 0, stream>>>(x, xb, NROWS * KDIM / 4);
  cvt_f32_to_bf16<<<1024, 256, 0, stream>>>(w, wb, ODIM * KDIM / 4);
  gemm_bt_bf16<<<512, 256, 0, stream>>>(xb, wb, bias, out);
}